// Round 6
// baseline (683.001 us; speedup 1.0000x reference)
//
#include <hip/hip_runtime.h>
#include <math.h>

#define VOCAB   65536
#define HDIM    512
#define MLEN    16
#define NWORDS  8192
#define IHDIM   128      // char emb dim / LSTM input
#define HHDIM   256      // hidden per direction

#define TMW 32           // words per LSTM block
#define TP  64           // words per projection block

// workspace byte offsets
#define B_WHH 0u          // 1 MB: [2][8 kt][64 ntg][64 lane] uint4 f16 W_hh B-frags
#define B_GX2 1048576u    // 4 MB: [2][256 cid][512 tid] uint4 = 8 f16 (j = g*2+c)
#define B_PBF 5242880u    // 512 KB: [16 kt][32 nt][64 lane] uint4 f16 proj B-frags
#define B_PBB 5767168u    // 2 KB: proj bias f32[512]
#define B_CHE 5769216u    // 8 MB: [8192][512] f16 char-path embeddings
#define B_GXL 14157824u   // 2 MB: [2][1024 n][256 cid] f32 gate-x preacts
#define B_INT 16254976u   // ints: [0..15] cnt, [16..31] offs, [32..47] cursor, [48] total, [64..] sorted

typedef _Float16 f16x8 __attribute__((ext_vector_type(8)));
typedef float    f32x4 __attribute__((ext_vector_type(4)));
union U4H8 { uint4 u; f16x8 h; _Float16 e[8]; };

__device__ __forceinline__ unsigned packh2(float lo, float hi) {
    union { _Float16 h[2]; unsigned u; } v;
    v.h[0] = (_Float16)lo; v.h[1] = (_Float16)hi;
    return v.u;
}

__device__ __forceinline__ float sigf(float x)  { return 1.0f / (1.0f + __expf(-x)); }
__device__ __forceinline__ float tanh_f(float x){ return 1.0f - 2.0f / (__expf(2.0f * x) + 1.0f); }

// async global->LDS 16B per lane; lds base wave-uniform (writes base + lane*16)
__device__ __forceinline__ void load_lds_128(const void* g, void* l) {
    __builtin_amdgcn_global_load_lds((const __attribute__((address_space(1))) unsigned*)g,
                                     (__attribute__((address_space(3))) unsigned*)l, 16, 0, 0);
}

// ---- pack W_hh B-frags, proj B-frags, proj bias ----
__global__ void prep_k(const float* __restrict__ whhf, const float* __restrict__ whhb,
                       const float* __restrict__ projw, const float* __restrict__ projb,
                       char* __restrict__ wsb) {
    int i = blockIdx.x * blockDim.x + threadIdx.x;
    if (i < 65536) {   // 2 dirs * 8 kt * 64 ntg * 64 lanes
        int dir = i >> 15, r = i & 32767, kt = r >> 12, r2 = r & 4095, ntg = r2 >> 6, lane = r2 & 63;
        const float* whh = dir ? whhb : whhf;
        int n  = ntg * 16 + (lane & 15);
        int k0 = kt * 32 + (lane >> 4) * 8;
        unsigned q[4];
        #pragma unroll
        for (int jj = 0; jj < 4; ++jj)
            q[jj] = packh2(whh[n * HHDIM + k0 + 2 * jj], whh[n * HHDIM + k0 + 2 * jj + 1]);
        ((uint4*)(wsb + B_WHH))[i] = make_uint4(q[0], q[1], q[2], q[3]);
    }
    if (i < 32768) {   // 16 kt * 32 nt * 64 lanes (proj: B[k][j] = projw[j][k])
        int kt = i >> 11, r = i & 2047, nt = r >> 6, lane = r & 63;
        int j  = nt * 16 + (lane & 15);
        int k0 = kt * 32 + (lane >> 4) * 8;
        unsigned q[4];
        #pragma unroll
        for (int jj = 0; jj < 4; ++jj)
            q[jj] = packh2(projw[j * HDIM + k0 + 2 * jj], projw[j * HDIM + k0 + 2 * jj + 1]);
        ((uint4*)(wsb + B_PBF))[i] = make_uint4(q[0], q[1], q[2], q[3]);
    }
    if (i < 512) ((float*)(wsb + B_PBB))[i] = projb[i];
}

// ---- gxa: gxl[dir][n][cid] = W_ih[n,:].emb[cid] + b_ih[n] + b_hh[n]; W_ih read once ----
__global__ void gxa_k(const float* __restrict__ wihf, const float* __restrict__ wihb,
                      const float* __restrict__ bihf, const float* __restrict__ bhhf,
                      const float* __restrict__ bihb, const float* __restrict__ bhhb,
                      const float* __restrict__ chemb, char* __restrict__ wsb) {
    const int dir = blockIdx.x >> 5, nc = blockIdx.x & 31, n0 = nc * 32;
    __shared__ __align__(16) float swih[32 * IHDIM];   // 16 KB
    __shared__ float sb[32];
    const float* wih = dir ? wihb : wihf;
    const float* bih = dir ? bihb : bihf;
    const float* bhh = dir ? bhhb : bhhf;
    for (int i = threadIdx.x; i < 1024; i += 256)
        ((float4*)swih)[i] = ((const float4*)(wih + (size_t)n0 * IHDIM))[i];
    if (threadIdx.x < 32) sb[threadIdx.x] = bih[n0 + threadIdx.x] + bhh[n0 + threadIdx.x];
    __syncthreads();
    const int cid = threadIdx.x;
    float4 emb[32];
    #pragma unroll
    for (int k4 = 0; k4 < 32; ++k4) emb[k4] = ((const float4*)(chemb + cid * IHDIM))[k4];
    float* gxl = (float*)(wsb + B_GXL) + (size_t)dir * 262144;
    for (int n = 0; n < 32; ++n) {
        float acc = sb[n];
        const float4* w4 = (const float4*)(swih + n * IHDIM);
        #pragma unroll
        for (int k4 = 0; k4 < 32; ++k4) {
            float4 w = w4[k4], e = emb[k4];
            acc = fmaf(w.x, e.x, fmaf(w.y, e.y, fmaf(w.z, e.z, fmaf(w.w, e.w, acc))));
        }
        gxl[(size_t)(n0 + n) * 256 + cid] = acc;   // coalesced over cid
    }
}

// ---- pack gxl -> gx2 thread-major f16 ----
__global__ void pack_k(char* __restrict__ wsb) {
    int i = blockIdx.x * blockDim.x + threadIdx.x;   // < 262144
    int dir = i >> 17, r = i & 131071, cid = r >> 9, t2 = r & 511;
    int wv = t2 >> 6, col = t2 & 15;
    const float* gxl = (const float*)(wsb + B_GXL) + (size_t)dir * 262144;
    U4H8 v;
    #pragma unroll
    for (int j = 0; j < 8; ++j) {
        int g = j >> 1, c = j & 1;
        int n = g * 256 + wv * 32 + c * 16 + col;
        v.e[j] = (_Float16)gxl[(size_t)n * 256 + cid];
    }
    ((uint4*)(wsb + B_GX2))[i] = v.u;
}

// ---- counting sort of OOV word indices by length (descending) ----
__global__ void count_k(const int* __restrict__ is_oov, const int* __restrict__ lens,
                        int* __restrict__ ip) {
    int n = blockIdx.x * blockDim.x + threadIdx.x;
    if (n < NWORDS && is_oov[n] > 0) atomicAdd(&ip[lens[n] - 1], 1);
}

__global__ void prefix_k(int* __restrict__ ip) {
    if (threadIdx.x == 0) {
        int total = 0;
        for (int b = 15; b >= 0; --b) { ip[16 + b] = total; ip[32 + b] = total; total += ip[b]; }
        ip[48] = total;
    }
}

__global__ void scatter_k(const int* __restrict__ is_oov, const int* __restrict__ lens,
                          int* __restrict__ ip) {
    int n = blockIdx.x * blockDim.x + threadIdx.x;
    if (n < NWORDS && is_oov[n] > 0) {
        int pos = atomicAdd(&ip[32 + lens[n] - 1], 1);
        ip[64 + pos] = n;
    }
}

// ---- MFMA BiLSTM: flat grid (dir = b&1); kt 0..2 weights in VGPRs, kt 3..7 DMA-streamed ----
__global__ __launch_bounds__(512, 2)
void lstm_k(const int* __restrict__ char_ids, const int* __restrict__ lens,
            const char* __restrict__ wsb, const int* __restrict__ ip) {
    const int b = blockIdx.x;
    const int dir = b & 1;
    const int tid = threadIdx.x;
    const int total = ip[48];
    const int w0 = (b >> 1) * TMW;
    if (w0 >= total) return;
    const int wcount = min(TMW, total - w0);
    const int* sorted = ip + 64;

    __shared__ int n_s[TMW], len_s[TMW];
    __shared__ int cid_s[MLEN][TMW];
    __shared__ __align__(16) _Float16 Zh[TMW][264];     // 16.5 KB
    __shared__ __align__(16) uint4 wbuf[8][2][512];     // 128 KB

    if (tid < TMW) {
        int idx = w0 + min(tid, wcount - 1);
        n_s[tid] = sorted[idx];
        len_s[tid] = (tid < wcount) ? lens[sorted[idx]] : 0;
    }
    for (int i = tid; i < TMW * 132; i += 512) ((unsigned*)Zh)[i] = 0u;   // h0 = 0
    __syncthreads();
    {   // stage char ids (pre-reversed for bwd)
        int m = tid >> 4, t = tid & 15;
        int L = len_s[m];
        int pos = dir ? max(L - 1 - t, 0) : t;
        cid_s[t][m] = char_ids[n_s[m] * MLEN + pos];
    }

    const int wv = tid >> 6, lane = tid & 63, col = lane & 15, quad = lane >> 4;
    int lenr[2][4];
    #pragma unroll
    for (int mt = 0; mt < 2; ++mt)
        #pragma unroll
        for (int r = 0; r < 4; ++r) lenr[mt][r] = len_s[mt * 16 + quad * 4 + r];
    const int maxlen = len_s[0];    // sorted desc

    const uint4* wpg = (const uint4*)(wsb + B_WHH) + (size_t)dir * 32768;   // [kt][ntg][lane]
    const uint4* gx2 = (const uint4*)(wsb + B_GX2) + (size_t)dir * 131072;  // [cid][tid]

    // hold kt 0..2 B-frags in VGPRs (96 regs/lane), loaded once
    uint4 wreg[3][8];
    #pragma unroll
    for (int kt = 0; kt < 3; ++kt)
        #pragma unroll
        for (int gc = 0; gc < 8; ++gc) {
            int ntg = (gc >> 1) * 16 + wv * 2 + (gc & 1);
            wreg[kt][gc] = wpg[kt * 4096 + ntg * 64 + lane];
        }

    float cst[2][2][4];   // [c][mt][r]
    #pragma unroll
    for (int c = 0; c < 2; ++c)
        #pragma unroll
        for (int mt = 0; mt < 2; ++mt)
            #pragma unroll
            for (int r = 0; r < 4; ++r) cst[c][mt][r] = 0.0f;

    auto stage = [&](int kt, int buf) {   // wave-private: 8 chunks of 1 KB
        #pragma unroll
        for (int gc = 0; gc < 8; ++gc) {
            int ntg = (gc >> 1) * 16 + wv * 2 + (gc & 1);
            load_lds_128(wpg + (kt * 4096 + ntg * 64 + lane), &wbuf[wv][buf][gc * 64]);
        }
    };
    __syncthreads();

    for (int t = 0; t < maxlen; ++t) {
        stage(3, 1);    // drained by acc-init's vmcnt(0) below
        // C-init: one coalesced 16B load per (mt,r), thread-major packed
        U4H8 gq[2][4];
        #pragma unroll
        for (int mt = 0; mt < 2; ++mt)
            #pragma unroll
            for (int r = 0; r < 4; ++r)
                gq[mt][r].u = gx2[(size_t)cid_s[t][mt * 16 + quad * 4 + r] * 512 + tid];

        f32x4 acc[4][2][2];   // [g][c][mt]  (compiler waits vmcnt(0) for gq here)
        #pragma unroll
        for (int g = 0; g < 4; ++g)
            #pragma unroll
            for (int c = 0; c < 2; ++c)
                #pragma unroll
                for (int mt = 0; mt < 2; ++mt) {
                    f32x4 a;
                    #pragma unroll
                    for (int r = 0; r < 4; ++r) a[r] = (float)gq[mt][r].e[g * 2 + c];
                    acc[g][c][mt] = a;
                }

        #pragma unroll
        for (int kt = 0; kt < 8; ++kt) {
            if (kt == 0) stage(4, 0);
            if (kt >= 3 && kt < 7) __builtin_amdgcn_s_waitcnt(0x0F78);   // vmcnt(8)
            if (kt == 7)           __builtin_amdgcn_s_waitcnt(0x0F70);   // vmcnt(0)
            f16x8 af0 = *(const f16x8*)&Zh[col][kt * 32 + quad * 8];
            f16x8 af1 = *(const f16x8*)&Zh[16 + col][kt * 32 + quad * 8];
            #pragma unroll
            for (int gc = 0; gc < 8; ++gc) {
                U4H8 bf;
                if (kt < 3) bf.u = wreg[kt][gc];
                else        bf.u = wbuf[wv][kt & 1][gc * 64 + lane];
                const int g = gc >> 1, c = gc & 1;
                acc[g][c][0] = __builtin_amdgcn_mfma_f32_16x16x32_f16(af0, bf.h, acc[g][c][0], 0, 0, 0);
                acc[g][c][1] = __builtin_amdgcn_mfma_f32_16x16x32_f16(af1, bf.h, acc[g][c][1], 0, 0, 0);
            }
            if (kt == 3) stage(5, 1);
            if (kt == 4) stage(6, 0);
            if (kt == 5) stage(7, 1);
        }
        __syncthreads();   // all waves' A-reads done before h overwrite

        #pragma unroll
        for (int mt = 0; mt < 2; ++mt)
            #pragma unroll
            for (int r = 0; r < 4; ++r) {
                if (t < lenr[mt][r]) {
                    const int m = mt * 16 + quad * 4 + r;
                    #pragma unroll
                    for (int c = 0; c < 2; ++c) {
                        float i_ = sigf(acc[0][c][mt][r]);
                        float f_ = sigf(acc[1][c][mt][r]);
                        float g_ = tanh_f(acc[2][c][mt][r]);
                        float o_ = sigf(acc[3][c][mt][r]);
                        float cn = f_ * cst[c][mt][r] + i_ * g_;
                        cst[c][mt][r] = cn;
                        Zh[m][wv * 32 + c * 16 + col] = (_Float16)(o_ * tanh_f(cn));
                    }
                }
            }
        __syncthreads();   // h visible before next step's A-reads
    }

    unsigned short* cheh = (unsigned short*)(wsb + B_CHE);
    for (int i = tid; i < TMW * HHDIM; i += 512) {
        int m = i >> 8, u = i & 255;
        if (m < wcount) {
            union { _Float16 h; unsigned short s; } v; v.h = Zh[m][u];
            __builtin_nontemporal_store(v.s, cheh + (size_t)n_s[m] * HDIM + dir * HHDIM + u);
        }
    }
}

// ---- select + projection via f16 MFMA: 64 words/block, 512 thr ----
__global__ __launch_bounds__(512, 2)
void proj_k(const int* __restrict__ word_ids, const int* __restrict__ is_oov,
            const float* __restrict__ word_emb, const char* __restrict__ wsb,
            float* __restrict__ out) {
    const int tid = threadIdx.x;
    const int n0 = blockIdx.x * TP;
    __shared__ __align__(16) _Float16 Zp[TP][520];   // 66.6 KB

    for (int f = tid; f < TP * 128; f += 512) {      // 128 segs of 4 elems per word
        int w = f >> 7, s4 = f & 127;
        int n = n0 + w;
        if (is_oov[n] > 0) {
            ushort4 hv = ((const ushort4*)((const unsigned short*)(wsb + B_CHE) + (size_t)n * HDIM))[s4];
            *(ushort4*)&Zp[w][s4 * 4] = hv;
        } else {
            float4 v = ((const float4*)(word_emb + (size_t)word_ids[n] * HDIM))[s4];
            Zp[w][s4 * 4 + 0] = (_Float16)v.x;
            Zp[w][s4 * 4 + 1] = (_Float16)v.y;
            Zp[w][s4 * 4 + 2] = (_Float16)v.z;
            Zp[w][s4 * 4 + 3] = (_Float16)v.w;
        }
    }
    __syncthreads();

    const int wv = tid >> 6, lane = tid & 63, col = lane & 15, quad = lane >> 4;
    const float* pbb = (const float*)(wsb + B_PBB);
    f32x4 acc[4][4];   // [c][mtile]
    #pragma unroll
    for (int c = 0; c < 4; ++c) {
        float bv = pbb[wv * 64 + c * 16 + col];
        #pragma unroll
        for (int mt = 0; mt < 4; ++mt) acc[c][mt] = (f32x4){bv, bv, bv, bv};
    }

    const uint4* pbf = (const uint4*)(wsb + B_PBF);
    #pragma unroll
    for (int kt = 0; kt < 16; ++kt) {
        f16x8 af[4];
        #pragma unroll
        for (int mt = 0; mt < 4; ++mt)
            af[mt] = *(const f16x8*)&Zp[mt * 16 + col][kt * 32 + quad * 8];
        #pragma unroll
        for (int c = 0; c < 4; ++c) {
            U4H8 bf; bf.u = pbf[(size_t)kt * 2048 + (wv * 4 + c) * 64 + lane];
            #pragma unroll
            for (int mt = 0; mt < 4; ++mt)
                acc[c][mt] = __builtin_amdgcn_mfma_f32_16x16x32_f16(af[mt], bf.h, acc[c][mt], 0, 0, 0);
        }
    }

    #pragma unroll
    for (int mt = 0; mt < 4; ++mt)
        #pragma unroll
        for (int r = 0; r < 4; ++r) {
            const size_t m = n0 + mt * 16 + quad * 4 + r;
            #pragma unroll
            for (int c = 0; c < 4; ++c)
                __builtin_nontemporal_store(acc[c][mt][r], &out[m * HDIM + wv * 64 + c * 16 + col]);
        }
}

extern "C" void kernel_launch(void* const* d_in, const int* in_sizes, int n_in,
                              void* d_out, int out_size, void* d_ws, size_t ws_size,
                              hipStream_t stream) {
    const int*   word_ids  = (const int*)d_in[0];
    const int*   is_oov    = (const int*)d_in[1];
    const int*   char_ids  = (const int*)d_in[2];
    const int*   char_lens = (const int*)d_in[3];
    const float* word_emb  = (const float*)d_in[4];
    const float* char_emb  = (const float*)d_in[5];
    const float* w_ih_f    = (const float*)d_in[6];
    const float* w_hh_f    = (const float*)d_in[7];
    const float* b_ih_f    = (const float*)d_in[8];
    const float* b_hh_f    = (const float*)d_in[9];
    const float* w_ih_b    = (const float*)d_in[10];
    const float* w_hh_b    = (const float*)d_in[11];
    const float* b_ih_b    = (const float*)d_in[12];
    const float* b_hh_b    = (const float*)d_in[13];
    const float* proj_w    = (const float*)d_in[14];
    const float* proj_b    = (const float*)d_in[15];
    float* out = (float*)d_out;
    char*  wsb = (char*)d_ws;
    int*   ip  = (int*)(wsb + B_INT);

    hipMemsetAsync(ip, 0, 256, stream);
    prep_k<<<256, 256, 0, stream>>>(w_hh_f, w_hh_b, proj_w, proj_b, wsb);
    gxa_k<<<64, 256, 0, stream>>>(w_ih_f, w_ih_b, b_ih_f, b_hh_f, b_ih_b, b_hh_b, char_emb, wsb);
    pack_k<<<1024, 256, 0, stream>>>(wsb);
    count_k<<<NWORDS / 256, 256, 0, stream>>>(is_oov, char_lens, ip);
    prefix_k<<<1, 64, 0, stream>>>(ip);
    scatter_k<<<NWORDS / 256, 256, 0, stream>>>(is_oov, char_lens, ip);
    lstm_k<<<2 * (NWORDS / TMW), 512, 0, stream>>>(char_ids, char_lens, wsb, ip);
    proj_k<<<NWORDS / TP, 512, 0, stream>>>(word_ids, is_oov, word_emb, wsb, out);
}